// Round 1
// 578.128 us; speedup vs baseline: 1.0281x; 1.0281x over previous
//
#include <hip/hip_runtime.h>
#include <hip/hip_bf16.h>
#include <cstddef>
#include <cstdint>

// ---------------------------------------------------------------------------
//  heatmap  (16, 64, 256, 256)  f32
//  pos_embed(16, 32, 256, 256)  f32
//  feat1    (16, 96, 128, 128)  f32
//  feat2    (16,384,  64,  64)  f32
//  feat3    (16,512,  32,  32)  f32
//  W1 (992,1024) ; W2(1024,512) ; W3(512,256) ; W4(256,224)  + biases
//  out (16, 256, 64) f32 : ch 0..223 = MLP out (transposed), 224..255 = positions
//
//  Pipeline:
//   K1: fused [argmax+gather] (blocks 0..1023) + [weight transpose/cast]
//       (blocks 1024..2711) -- one launch
//   K2-K5: MFMA bf16 GEMMs, split-K x4: one 256-thread block per 32x32 tile,
//       wave w takes k-steps w, w+4, ... ; partials reduced via padded LDS.
//       (round-3 change: was 1 wave/tile = 1 wave/SIMD, 31-deep serial
//        L2-latency chain; now 16 waves/CU and 4x shorter chain.)
//
//  NOTE (round-2 finding): ~480 us of dur_us is harness restore/poison
//  (1 GB ws fill @160 us etc.) inside the timed window — fixed overhead.
// ---------------------------------------------------------------------------

typedef __attribute__((ext_vector_type(8))) short bf16x8;   // 8 bf16 = 4 VGPRs
typedef __attribute__((ext_vector_type(4))) float f32x4;

// ---- bilinear gather helper ----------------------------------------------
__device__ inline void bilinear_block(const float* __restrict__ fb, int C, int H, int W,
                                      float gx, float gy,
                                      __hip_bfloat16* __restrict__ dst, int tid) {
    const float x = (gx + 1.0f) * 0.5f * (float)(W - 1);
    const float y = (gy + 1.0f) * 0.5f * (float)(H - 1);
    const float x0f = floorf(x), y0f = floorf(y);
    const float wx = x - x0f, wy = y - y0f;
    const int x0 = (int)fminf(fmaxf(x0f,       0.f), (float)(W - 1));
    const int x1 = (int)fminf(fmaxf(x0f + 1.f, 0.f), (float)(W - 1));
    const int y0 = (int)fminf(fmaxf(y0f,       0.f), (float)(H - 1));
    const int y1 = (int)fminf(fmaxf(y0f + 1.f, 0.f), (float)(H - 1));
    const float w00 = (1.f - wx) * (1.f - wy);
    const float w01 = wx * (1.f - wy);
    const float w10 = (1.f - wx) * wy;
    const float w11 = wx * wy;
    const int i00 = y0 * W + x0, i01 = y0 * W + x1;
    const int i10 = y1 * W + x0, i11 = y1 * W + x1;
    const size_t HW = (size_t)H * W;
    for (int c = tid; c < C; c += 256) {
        const float* fc = fb + (size_t)c * HW;
        float v = fc[i00] * w00 + fc[i01] * w01 + fc[i10] * w10 + fc[i11] * w11;
        dst[c] = __float2bfloat16(v);
    }
}

// ---- K1: fused argmax+gather (blocks 0..1023) + wcast (blocks 1024..2711) -
__global__ __launch_bounds__(256) void fused_front_kernel(
    const float* __restrict__ hm,
    const float* __restrict__ pos_embed,
    const float* __restrict__ feat1, const float* __restrict__ feat2,
    const float* __restrict__ feat3,
    const float* __restrict__ W1, const float* __restrict__ W2,
    const float* __restrict__ W3, const float* __restrict__ W4,
    __hip_bfloat16* __restrict__ T1, __hip_bfloat16* __restrict__ T2,
    __hip_bfloat16* __restrict__ T3, __hip_bfloat16* __restrict__ T4,
    __hip_bfloat16* __restrict__ X0, float* __restrict__ out) {
    __shared__ float smem[32 * 33];            // wcast tile; argmax uses 8 slots
    float* sval = smem;                        // [4]
    int*   sidx = (int*)(smem + 4);            // [4]
    const int tid = threadIdx.x;

    if (blockIdx.x >= 1024) {
        // ---------------- weight transpose + cast ----------------
        int bid = blockIdx.x - 1024;
        const float* W; __hip_bfloat16* T; int K, N;
        if (bid < 992)        { W = W1; T = T1; K = 992;  N = 1024; }
        else if (bid < 1504)  { bid -= 992;  W = W2; T = T2; K = 1024; N = 512; }
        else if (bid < 1632)  { bid -= 1504; W = W3; T = T3; K = 512;  N = 256; }
        else                  { bid -= 1632; W = W4; T = T4; K = 256;  N = 224; }
        const int tilesN = N >> 5;
        const int tk = bid / tilesN, tn = bid - tk * tilesN;
        float (*tile)[33] = (float(*)[33])smem;
        const int col = tid & 31, rowg = tid >> 5;   // rowg 0..7
        #pragma unroll
        for (int i = 0; i < 4; ++i) {
            int k = (tk << 5) + rowg + (i << 3);
            tile[rowg + (i << 3)][col] = W[(size_t)k * N + (tn << 5) + col];
        }
        __syncthreads();
        #pragma unroll
        for (int i = 0; i < 4; ++i) {
            int n = (tn << 5) + rowg + (i << 3);
            T[(size_t)n * K + (tk << 5) + col] = __float2bfloat16(tile[col][rowg + (i << 3)]);
        }
        return;
    }

    // ---------------- per-plane argmax ----------------
    const int plane = blockIdx.x;               // b*64 + j
    const float4* p4 = (const float4*)(hm + (size_t)plane * 65536);
    float best = -3.402823466e38f;
    int bidx = 0;
    for (int i = tid; i < 16384; i += 256) {
        float4 v = p4[i];
        int base = i << 2;
        if (v.x > best) { best = v.x; bidx = base; }
        if (v.y > best) { best = v.y; bidx = base + 1; }
        if (v.z > best) { best = v.z; bidx = base + 2; }
        if (v.w > best) { best = v.w; bidx = base + 3; }
    }
    // wave-level shuffle reduce (64 lanes), tie-break lowest index
    #pragma unroll
    for (int off = 32; off > 0; off >>= 1) {
        float ov = __shfl_down(best, off);
        int   oi = __shfl_down(bidx, off);
        if (ov > best || (ov == best && oi < bidx)) { best = ov; bidx = oi; }
    }
    if ((tid & 63) == 0) { sval[tid >> 6] = best; sidx[tid >> 6] = bidx; }
    __syncthreads();
    float bv = sval[0]; int bi = sidx[0];
    #pragma unroll
    for (int w2 = 1; w2 < 4; ++w2) {
        float ov = sval[w2]; int oi = sidx[w2];
        if (ov > bv || (ov == bv && oi < bi)) { bv = ov; bi = oi; }
    }
    const int idx = bi;

    // ---------------- gather (same block, no round-trip) ----------------
    const int b = plane >> 6, j = plane & 63;
    const int py = idx >> 8, px = idx & 255;
    const float gx = ((float)px - 127.5f) / 127.5f;
    const float gy = ((float)py - 127.5f) / 127.5f;

    if (tid < 32) {
        float v = pos_embed[((size_t)(b * 32 + tid)) * 65536 + idx];
        out[(size_t)b * 16384 + (size_t)(224 + tid) * 64 + j] = v;
    }

    __hip_bfloat16* xrow = X0 + (size_t)plane * 992;
    bilinear_block(feat1 + (size_t)b *  96 * 128 * 128,  96, 128, 128, gx, gy, xrow,       tid);
    bilinear_block(feat2 + (size_t)b * 384 *  64 *  64, 384,  64,  64, gx, gy, xrow +  96, tid);
    bilinear_block(feat3 + (size_t)b * 512 *  32 *  32, 512,  32,  32, gx, gy, xrow + 480, tid);
}

// ---- K2-K5: MFMA bf16 GEMM, split-K x4, one 256-thread block per tile ----
// A: [M][K] bf16 row-major. Bt: [N][K] bf16 (W transposed). Y=relu(A@W+b).
// Wave w accumulates k-steps {w, w+4, ...}; partials summed through LDS.
// C/D frag: col = lane&15, row = (lane>>4)*4 + reg   [learn_hip m89/m91]
template<bool LAST>
__global__ __launch_bounds__(256) void mfma_gemm_sk(
    const short* __restrict__ A, const short* __restrict__ Bt,
    const float* __restrict__ bias, void* __restrict__ Yv,
    int N, int K) {
    __shared__ float red[4 * 64 * 17];           // stride 17: conflict-free
    const int tid = threadIdx.x;
    const int w = tid >> 6, lane = tid & 63;
    const int q = lane >> 4, r = lane & 15;
    const int m0 = blockIdx.y << 5;
    const int n0 = blockIdx.x << 5;

    const short* pa0 = A  + (size_t)(m0 + r) * K + (q << 3);
    const short* pa1 = pa0 + (size_t)16 * K;
    const short* pb0 = Bt + (size_t)(n0 + r) * K + (q << 3);
    const short* pb1 = pb0 + (size_t)16 * K;

    f32x4 acc00 = {0.f,0.f,0.f,0.f}, acc01 = {0.f,0.f,0.f,0.f};
    f32x4 acc10 = {0.f,0.f,0.f,0.f}, acc11 = {0.f,0.f,0.f,0.f};

    const int nk = K >> 5;                       // 31 / 32 / 16 / 8 (all >= 4)
    int ks = w;
    {
        int off = ks << 5;
        bf16x8 a0 = *(const bf16x8*)(pa0 + off);
        bf16x8 a1 = *(const bf16x8*)(pa1 + off);
        bf16x8 b0 = *(const bf16x8*)(pb0 + off);
        bf16x8 b1 = *(const bf16x8*)(pb1 + off);
        for (ks += 4; ks < nk; ks += 4) {
            int o2 = ks << 5;
            bf16x8 na0 = *(const bf16x8*)(pa0 + o2);
            bf16x8 na1 = *(const bf16x8*)(pa1 + o2);
            bf16x8 nb0 = *(const bf16x8*)(pb0 + o2);
            bf16x8 nb1 = *(const bf16x8*)(pb1 + o2);
            acc00 = __builtin_amdgcn_mfma_f32_16x16x32_bf16(a0, b0, acc00, 0, 0, 0);
            acc01 = __builtin_amdgcn_mfma_f32_16x16x32_bf16(a0, b1, acc01, 0, 0, 0);
            acc10 = __builtin_amdgcn_mfma_f32_16x16x32_bf16(a1, b0, acc10, 0, 0, 0);
            acc11 = __builtin_amdgcn_mfma_f32_16x16x32_bf16(a1, b1, acc11, 0, 0, 0);
            a0 = na0; a1 = na1; b0 = nb0; b1 = nb1;
        }
        acc00 = __builtin_amdgcn_mfma_f32_16x16x32_bf16(a0, b0, acc00, 0, 0, 0);
        acc01 = __builtin_amdgcn_mfma_f32_16x16x32_bf16(a0, b1, acc01, 0, 0, 0);
        acc10 = __builtin_amdgcn_mfma_f32_16x16x32_bf16(a1, b0, acc10, 0, 0, 0);
        acc11 = __builtin_amdgcn_mfma_f32_16x16x32_bf16(a1, b1, acc11, 0, 0, 0);
    }

    // partials -> LDS.  slot layout per lane: [acc00[0..3] acc01[0..3] acc10[0..3] acc11[0..3]]
    float* myrow = red + (size_t)(w * 64 + lane) * 17;
    #pragma unroll
    for (int i = 0; i < 4; ++i) {
        myrow[i]      = acc00[i];
        myrow[4 + i]  = acc01[i];
        myrow[8 + i]  = acc10[i];
        myrow[12 + i] = acc11[i];
    }
    __syncthreads();

    // all 256 threads reduce: 4 output elements each (e = tid + 256*j)
    #pragma unroll
    for (int jj = 0; jj < 4; ++jj) {
        const int e = tid + (jj << 8);           // 0..1023
        const int le = e >> 4, s = e & 15;
        const int which = s >> 2, i = s & 3;
        float v = red[(0 * 64 + le) * 17 + s] + red[(1 * 64 + le) * 17 + s]
                + red[(2 * 64 + le) * 17 + s] + red[(3 * 64 + le) * 17 + s];
        const int qe = le >> 4, re = le & 15;
        const int row = m0 + (qe << 2) + i + ((which & 2) ? 16 : 0);
        const int col = n0 + re + ((which & 1) ? 16 : 0);
        v = fmaxf(v + bias[col], 0.f);
        if (LAST) {
            // out[b, n, j]: m = b*64 + j ; stride (16384, 64, 1)
            float* O = (float*)Yv;
            O[(size_t)(row >> 6) * 16384 + (size_t)col * 64 + (row & 63)] = v;
        } else {
            __hip_bfloat16* Y = (__hip_bfloat16*)Yv;
            Y[(size_t)row * N + col] = __float2bfloat16(v);
        }
    }
}

extern "C" void kernel_launch(void* const* d_in, const int* in_sizes, int n_in,
                              void* d_out, int out_size, void* d_ws, size_t ws_size,
                              hipStream_t stream) {
    (void)in_sizes; (void)n_in; (void)out_size; (void)ws_size;
    const float* heatmap   = (const float*)d_in[0];
    const float* pos_embed = (const float*)d_in[1];
    const float* feat1     = (const float*)d_in[2];
    const float* feat2     = (const float*)d_in[3];
    const float* feat3     = (const float*)d_in[4];
    const float* W1 = (const float*)d_in[5];  const float* b1 = (const float*)d_in[6];
    const float* W2 = (const float*)d_in[7];  const float* b2 = (const float*)d_in[8];
    const float* W3 = (const float*)d_in[9];  const float* b3 = (const float*)d_in[10];
    const float* W4 = (const float*)d_in[11]; const float* b4 = (const float*)d_in[12];
    float* out = (float*)d_out;

    char* ws = (char*)d_ws;
    short* X0 = (short*)(ws + 8192);                  // 1024 x 992  bf16
    short* X1 = X0 + (size_t)1024 * 992;              // 1024 x 1024 bf16
    short* X2 = X1 + (size_t)1024 * 1024;             // 1024 x 512  bf16
    short* X3 = X2 + (size_t)1024 * 512;              // 1024 x 256  bf16
    short* T1 = X3 + (size_t)1024 * 256;              // 1024 x 992  bf16 (W1^T)
    short* T2 = T1 + (size_t)1024 * 992;              // 512  x 1024 bf16 (W2^T)
    short* T3 = T2 + (size_t)512 * 1024;              // 256  x 512  bf16 (W3^T)
    short* T4 = T3 + (size_t)256 * 512;               // 224  x 256  bf16 (W4^T)

    fused_front_kernel<<<2712, 256, 0, stream>>>(
        heatmap, pos_embed, feat1, feat2, feat3,
        W1, W2, W3, W4,
        (__hip_bfloat16*)T1, (__hip_bfloat16*)T2, (__hip_bfloat16*)T3, (__hip_bfloat16*)T4,
        (__hip_bfloat16*)X0, out);
    mfma_gemm_sk<false><<<dim3(32, 32), 256, 0, stream>>>(X0, T1, b1, X1, 1024,  992);
    mfma_gemm_sk<false><<<dim3(16, 32), 256, 0, stream>>>(X1, T2, b2, X2,  512, 1024);
    mfma_gemm_sk<false><<<dim3( 8, 32), 256, 0, stream>>>(X2, T3, b3, X3,  256,  512);
    mfma_gemm_sk<true ><<<dim3( 7, 32), 256, 0, stream>>>(X3, T4, b4, out,  224,  256);
}